// Round 6
// baseline (165.490 us; speedup 1.0000x reference)
//
#include <hip/hip_runtime.h>
#include <hip/hip_bf16.h>

// Problem constants
#define B_  4096
#define T_  80
#define E_  100
#define U_  64
#define G_  256    // 4*U
#define V_  10000

#define S_H  72    // hbuf row stride (bf16 elems), 144B rows (16B aligned)
#define AS   136   // embk A-tile LDS stride (bf16): 272B rows, 16B aligned, %8==0

typedef __attribute__((ext_vector_type(8))) __bf16 bf16x8;
typedef __attribute__((ext_vector_type(4))) __bf16 bf16x4;
typedef __attribute__((ext_vector_type(4))) float  floatx4;

__device__ __forceinline__ float sigmoidf_(float x) {
    return __fdividef(1.f, 1.f + __expf(-x));
}

__device__ __forceinline__ float tanhf_(float x) {
    // 1 - 2/(e^{2x}+1): monotone, saturates correctly, no NaN
    return 1.f - __fdividef(2.f, __expf(2.f * x) + 1.f);
}

// ---------------------------------------------------------------------------
// Kernel A (MFMA): embk[v][g] = b1[g] + emb[v] . k1[:,g]   (unchanged from R4)
// ---------------------------------------------------------------------------
__global__ __launch_bounds__(256) void embk_kernel(const float* __restrict__ emb,
                                                   const float* __restrict__ k1,
                                                   const float* __restrict__ b1,
                                                   float* __restrict__ embk) {
    __shared__ __bf16 aLDS[64 * AS];         // 17.4 KB

    const int tid  = threadIdx.x;
    const int lane = tid & 63;
    const int w    = tid >> 6;               // wave: owns cols n0 + [w*32, w*32+32)
    const int n    = lane & 15;
    const int kg   = lane >> 4;
    const int v0   = (blockIdx.x >> 1) * 64;
    const int n0   = (blockIdx.x & 1) * 128;
    const int nrows = min(64, V_ - v0);

    for (int i = tid; i < 64 * AS / 8; i += 256) {
        bf16x8 z;
#pragma unroll
        for (int jj = 0; jj < 8; ++jj) z[jj] = (__bf16)0.f;
        *(bf16x8*)(aLDS + i * 8) = z;
    }

    bf16x8 bfr[2][4];
#pragma unroll
    for (int ct = 0; ct < 2; ++ct)
#pragma unroll
        for (int kc = 0; kc < 4; ++kc) {
            bf16x8 s;
#pragma unroll
            for (int jj = 0; jj < 8; ++jj) {
                int k = kc * 32 + kg * 8 + jj;
                s[jj] = (k < E_) ? (__bf16)k1[k * G_ + n0 + w * 32 + ct * 16 + n]
                                 : (__bf16)0.f;
            }
            bfr[ct][kc] = s;
        }
    const float bv0 = b1[n0 + w * 32 + n];
    const float bv1 = b1[n0 + w * 32 + 16 + n];

    __syncthreads();                         // zeroing done

    for (int i = tid; i < nrows * 25; i += 256) {
        int r = i / 25, q = i - r * 25;
        float4 ev = *(const float4*)(emb + (long)(v0 + r) * E_ + q * 4);
        bf16x4 bv; bv[0] = (__bf16)ev.x; bv[1] = (__bf16)ev.y;
                   bv[2] = (__bf16)ev.z; bv[3] = (__bf16)ev.w;
        *(bf16x4*)(aLDS + r * AS + q * 4) = bv;
    }
    __syncthreads();

#pragma unroll
    for (int mt = 0; mt < 4; ++mt) {
        const __bf16* ab = aLDS + (mt * 16 + n) * AS + kg * 8;
        bf16x8 a0 = *(const bf16x8*)(ab + 0);
        bf16x8 a1 = *(const bf16x8*)(ab + 32);
        bf16x8 a2 = *(const bf16x8*)(ab + 64);
        bf16x8 a3 = *(const bf16x8*)(ab + 96);
#pragma unroll
        for (int ct = 0; ct < 2; ++ct) {
            float bv = ct ? bv1 : bv0;
            floatx4 acc = {bv, bv, bv, bv};
            acc = __builtin_amdgcn_mfma_f32_16x16x32_bf16(a0, bfr[ct][0], acc, 0, 0, 0);
            acc = __builtin_amdgcn_mfma_f32_16x16x32_bf16(a1, bfr[ct][1], acc, 0, 0, 0);
            acc = __builtin_amdgcn_mfma_f32_16x16x32_bf16(a2, bfr[ct][2], acc, 0, 0, 0);
            acc = __builtin_amdgcn_mfma_f32_16x16x32_bf16(a3, bfr[ct][3], acc, 0, 0, 0);
#pragma unroll
            for (int r = 0; r < 4; ++r) {
                int v = v0 + mt * 16 + kg * 4 + r;
                if (v < V_) embk[(long)v * G_ + n0 + w * 32 + ct * 16 + n] = acc[r];
            }
        }
    }
}

// ---------------------------------------------------------------------------
// Kernel B: recurrence. 256 blocks x 1024 threads (16 waves = 4/SIMD).
// Block = 16 batch rows. Wave w: w4 = w&3 picks unit chunk [w4*16, w4*16+16)
// (col-tiles {w4, w4+4, w4+8, w4+12} = that chunk's i,f,g,o columns);
// role = w>>2 in {0..3} picks ONE accumulator register -> each lane owns
// exactly 1 live cell (row kg*4+role, unit cb). MFMA is 4x-redundant (cheap,
// MfmaUtil ~10%). xk gathers (4/lane/step) are issued at the TOP of the step
// so they're in flight ~a full step before the barrier's vmcnt(0) drain;
// ping-pong registers + 2x unroll avoid copies. ONE barrier per step.
// ---------------------------------------------------------------------------
__global__ __launch_bounds__(1024, 4) void lstm_kernel(const int*   __restrict__ tokens,
                                                       const float* __restrict__ embk,
                                                       const float* __restrict__ r1,
                                                       const float* __restrict__ Wd,
                                                       const float* __restrict__ bd,
                                                       float* __restrict__ out) {
    __shared__ int    tokLDS[16 * T_];       // 5.12 KB
    __shared__ __bf16 hbuf[2][16 * S_H];     // 4.6 KB

    const int tid  = threadIdx.x;
    const int lane = tid & 63;
    const int w    = tid >> 6;               // 0..15
    const int w4   = w & 3;                  // unit chunk
    const int role = w >> 2;                 // acc register index 0..3
    const int n    = lane & 15;
    const int kg   = lane >> 4;
    const int bb   = blockIdx.x * 16;
    const int cb   = w4 * 16 + n;            // this lane's unit column u
    const int brow = kg * 4 + role;          // this lane's batch row

    for (int i = tid; i < 16 * T_; i += 1024) tokLDS[i] = tokens[bb * T_ + i];
    for (int i = tid; i < 2 * 16 * S_H; i += 1024) (&hbuf[0][0])[i] = (__bf16)0.f;

    // r1 B-fragments (VGPR-resident): col = j*64 + cb, k = kc*32 + kg*8 + jj
    bf16x8 bfr[4][2];
#pragma unroll
    for (int j = 0; j < 4; ++j)
#pragma unroll
        for (int kc = 0; kc < 2; ++kc) {
            bf16x8 s;
#pragma unroll
            for (int jj = 0; jj < 8; ++jj)
                s[jj] = (__bf16)r1[(kc * 32 + kg * 8 + jj) * G_ + j * 64 + cb];
            bfr[j][kc] = s;
        }

    float c = 0.f;                           // cell state for (brow, cb)

    __syncthreads();                         // tokens + zeroed hbuf visible

    // xk for t=0 (in flight; compiler waits before first use)
    float xkA[4], xkB[4];
    {
        const float* p = embk + (long)tokLDS[brow * T_ + 0] * G_;
#pragma unroll
        for (int j = 0; j < 4; ++j) xkA[j] = p[j * 64 + cb];
    }

    auto step = [&](int t, float* pf, const float* use) {
        // prefetch xk for step t+1 FIRST: in flight through ds_read + MFMA +
        // gate math, so the pre-barrier vmcnt(0) drain is ~free
        if (t + 1 < T_) {
            const float* p = embk + (long)tokLDS[brow * T_ + t + 1] * G_;
#pragma unroll
            for (int j = 0; j < 4; ++j) pf[j] = p[j * 64 + cb];
        }

        // A-fragments of h_{t-1}: A[m][k], m = n, k = kg*8 + jj
        const __bf16* hb = hbuf[(t + 1) & 1];
        bf16x8 a0 = *(const bf16x8*)(hb + n * S_H + kg * 8);
        bf16x8 a1 = *(const bf16x8*)(hb + n * S_H + 32 + kg * 8);

        floatx4 acc[4];
#pragma unroll
        for (int j = 0; j < 4; ++j) {
            floatx4 a = {0.f, 0.f, 0.f, 0.f};
            a = __builtin_amdgcn_mfma_f32_16x16x32_bf16(a0, bfr[j][0], a, 0, 0, 0);
            a = __builtin_amdgcn_mfma_f32_16x16x32_bf16(a1, bfr[j][1], a, 0, 0, 0);
            acc[j] = a;
        }

        // role-uniform register extraction (wave-uniform branch, no spill)
        float zi, zf, zg, zo;
        if      (role == 0) { zi = acc[0][0]; zf = acc[1][0]; zg = acc[2][0]; zo = acc[3][0]; }
        else if (role == 1) { zi = acc[0][1]; zf = acc[1][1]; zg = acc[2][1]; zo = acc[3][1]; }
        else if (role == 2) { zi = acc[0][2]; zf = acc[1][2]; zg = acc[2][2]; zo = acc[3][2]; }
        else                { zi = acc[0][3]; zf = acc[1][3]; zg = acc[2][3]; zo = acc[3][3]; }
        zi += use[0]; zf += use[1]; zg += use[2]; zo += use[3];

        float cn = sigmoidf_(zf) * c + sigmoidf_(zi) * tanhf_(zg);
        float hn = sigmoidf_(zo) * tanhf_(cn);
        c = cn;
        hbuf[t & 1][brow * S_H + cb] = (__bf16)hn;

        __syncthreads();                     // h_t visible; WAR on hbuf
    };

    for (int t = 0; t < T_; t += 2) {
        step(t,     xkB, xkA);               // prefetch into B, consume A
        step(t + 1, xkA, xkB);               // prefetch into A, consume B
    }

    // out[b] = sigmoid(h_final[b] . Wd + bd); h_79 in hbuf[1]
    if (tid < 16) {
        const __bf16* hb = hbuf[1] + tid * S_H;
        float s = bd[0];
#pragma unroll
        for (int u = 0; u < U_; ++u) s = fmaf((float)hb[u], Wd[u], s);
        out[bb + tid] = sigmoidf_(s);
    }
}

// ---------------------------------------------------------------------------
extern "C" void kernel_launch(void* const* d_in, const int* in_sizes, int n_in,
                              void* d_out, int out_size, void* d_ws, size_t ws_size,
                              hipStream_t stream) {
    const int*   tokens = (const int*)  d_in[0];
    const float* emb    = (const float*)d_in[1];
    // d_in[2..4] = k0, r0, b0 : dead in the reference (cell0 state unused)
    const float* k1     = (const float*)d_in[5];
    const float* r1     = (const float*)d_in[6];
    const float* b1     = (const float*)d_in[7];
    const float* Wd     = (const float*)d_in[8];
    const float* bd     = (const float*)d_in[9];
    float*       out    = (float*)d_out;

    float* embk = (float*)d_ws;              // V_*G_ floats = 10.24 MB

    embk_kernel<<<((V_ + 63) / 64) * 2, 256, 0, stream>>>(emb, k1, b1, embk);
    lstm_kernel<<<B_ / 16, 1024, 0, stream>>>(tokens, embk, r1, Wd, bd, out);
}

// Round 7
// 159.631 us; speedup vs baseline: 1.0367x; 1.0367x over previous
//
#include <hip/hip_runtime.h>
#include <hip/hip_bf16.h>

// Problem constants
#define B_  4096
#define T_  80
#define E_  100
#define U_  64
#define G_  256    // 4*U
#define V_  10000

#define S_H  72    // hbuf row stride (bf16 elems), 144B rows (16B aligned)
#define AS   136   // embk A-tile LDS stride (bf16): 272B rows, 16B aligned, %8==0

typedef __attribute__((ext_vector_type(8))) __bf16 bf16x8;
typedef __attribute__((ext_vector_type(4))) __bf16 bf16x4;
typedef __attribute__((ext_vector_type(4))) float  floatx4;

__device__ __forceinline__ float sigmoidf_(float x) {
    return __fdividef(1.f, 1.f + __expf(-x));
}

__device__ __forceinline__ float tanhf_(float x) {
    // 1 - 2/(e^{2x}+1): monotone, saturates correctly, no NaN
    return 1.f - __fdividef(2.f, __expf(2.f * x) + 1.f);
}

// ---------------------------------------------------------------------------
// Kernel A (MFMA): embk[v][g] = b1[g] + emb[v] . k1[:,g]   (unchanged, known-good)
// ---------------------------------------------------------------------------
__global__ __launch_bounds__(256) void embk_kernel(const float* __restrict__ emb,
                                                   const float* __restrict__ k1,
                                                   const float* __restrict__ b1,
                                                   float* __restrict__ embk) {
    __shared__ __bf16 aLDS[64 * AS];         // 17.4 KB

    const int tid  = threadIdx.x;
    const int lane = tid & 63;
    const int w    = tid >> 6;               // wave: owns cols n0 + [w*32, w*32+32)
    const int n    = lane & 15;
    const int kg   = lane >> 4;
    const int v0   = (blockIdx.x >> 1) * 64;
    const int n0   = (blockIdx.x & 1) * 128;
    const int nrows = min(64, V_ - v0);

    for (int i = tid; i < 64 * AS / 8; i += 256) {
        bf16x8 z;
#pragma unroll
        for (int jj = 0; jj < 8; ++jj) z[jj] = (__bf16)0.f;
        *(bf16x8*)(aLDS + i * 8) = z;
    }

    bf16x8 bfr[2][4];
#pragma unroll
    for (int ct = 0; ct < 2; ++ct)
#pragma unroll
        for (int kc = 0; kc < 4; ++kc) {
            bf16x8 s;
#pragma unroll
            for (int jj = 0; jj < 8; ++jj) {
                int k = kc * 32 + kg * 8 + jj;
                s[jj] = (k < E_) ? (__bf16)k1[k * G_ + n0 + w * 32 + ct * 16 + n]
                                 : (__bf16)0.f;
            }
            bfr[ct][kc] = s;
        }
    const float bv0 = b1[n0 + w * 32 + n];
    const float bv1 = b1[n0 + w * 32 + 16 + n];

    __syncthreads();                         // zeroing done

    for (int i = tid; i < nrows * 25; i += 256) {
        int r = i / 25, q = i - r * 25;
        float4 ev = *(const float4*)(emb + (long)(v0 + r) * E_ + q * 4);
        bf16x4 bv; bv[0] = (__bf16)ev.x; bv[1] = (__bf16)ev.y;
                   bv[2] = (__bf16)ev.z; bv[3] = (__bf16)ev.w;
        *(bf16x4*)(aLDS + r * AS + q * 4) = bv;
    }
    __syncthreads();

#pragma unroll
    for (int mt = 0; mt < 4; ++mt) {
        const __bf16* ab = aLDS + (mt * 16 + n) * AS + kg * 8;
        bf16x8 a0 = *(const bf16x8*)(ab + 0);
        bf16x8 a1 = *(const bf16x8*)(ab + 32);
        bf16x8 a2 = *(const bf16x8*)(ab + 64);
        bf16x8 a3 = *(const bf16x8*)(ab + 96);
#pragma unroll
        for (int ct = 0; ct < 2; ++ct) {
            float bv = ct ? bv1 : bv0;
            floatx4 acc = {bv, bv, bv, bv};
            acc = __builtin_amdgcn_mfma_f32_16x16x32_bf16(a0, bfr[ct][0], acc, 0, 0, 0);
            acc = __builtin_amdgcn_mfma_f32_16x16x32_bf16(a1, bfr[ct][1], acc, 0, 0, 0);
            acc = __builtin_amdgcn_mfma_f32_16x16x32_bf16(a2, bfr[ct][2], acc, 0, 0, 0);
            acc = __builtin_amdgcn_mfma_f32_16x16x32_bf16(a3, bfr[ct][3], acc, 0, 0, 0);
#pragma unroll
            for (int r = 0; r < 4; ++r) {
                int v = v0 + mt * 16 + kg * 4 + r;
                if (v < V_) embk[(long)v * G_ + n0 + w * 32 + ct * 16 + n] = acc[r];
            }
        }
    }
}

// ---------------------------------------------------------------------------
// Kernel B: recurrence via TRANSPOSED MFMA: z^T = r1^T @ h^T.
// 256 blocks x 256 threads (4 waves = 1/SIMD). Block = 16 batch rows; wave w
// owns units [w*16, w*16+16) -> 4 gate-col tiles (one per gate), M = gate
// cols, N = batch rows. C-layout gives lane (n,kg): row n, units w*16+4kg+r
// (r=0..3), gates = acc[0..3][r] -> 4 fully-dense cells/lane, no
// redistribution, no dead lanes, no z LDS traffic.
//   - A = r1^T fragments: static, 32 VGPRs, loaded once.
//   - B = h^T from LDS: 2 x ds_read_b128 per step.
//   - C-init = xk float4 loads (gathered from embk), prefetched TWO steps
//     ahead so the pre-barrier vmcnt(0) drain is off the critical path.
//   - h_new: 4 consecutive bf16 -> one ds_write_b64. ONE barrier/step.
// ---------------------------------------------------------------------------
__global__ __launch_bounds__(256) void lstm_kernel(const int*   __restrict__ tokens,
                                                   const float* __restrict__ embk,
                                                   const float* __restrict__ r1,
                                                   const float* __restrict__ Wd,
                                                   const float* __restrict__ bd,
                                                   float* __restrict__ out) {
    __shared__ int    tokLDS[16 * T_];       // 5.12 KB
    __shared__ __bf16 hbuf[2][16 * S_H];     // 4.6 KB

    const int tid  = threadIdx.x;
    const int lane = tid & 63;
    const int w    = tid >> 6;               // unit block [w*16, w*16+16)
    const int n    = lane & 15;              // batch row (N-operand of MFMA)
    const int kg   = lane >> 4;              // 0..3
    const int bb   = blockIdx.x * 16;

    for (int i = tid; i < 16 * T_; i += 256) tokLDS[i] = tokens[bb * T_ + i];
    for (int i = tid; i < 2 * 16 * S_H; i += 256) (&hbuf[0][0])[i] = (__bf16)0.f;

    // A-fragments = r1^T (static): tile ct covers gate-cols ct*64 + w*16 + m,
    // A[m][k] = r1[k][ct*64 + w*16 + m]; lane holds m = n, k = kc*32 + kg*8 + jj
    bf16x8 afr[4][2];
#pragma unroll
    for (int ct = 0; ct < 4; ++ct)
#pragma unroll
        for (int kc = 0; kc < 2; ++kc) {
            bf16x8 s;
#pragma unroll
            for (int jj = 0; jj < 8; ++jj)
                s[jj] = (__bf16)r1[(kc * 32 + kg * 8 + jj) * G_ + ct * 64 + w * 16 + n];
            afr[ct][kc] = s;
        }

    // cell state: 4 cells/lane: (row n, unit w*16 + 4*kg + r)
    float c[4] = {0.f, 0.f, 0.f, 0.f};

    __syncthreads();                         // tokens + zeroed hbuf visible

    // xk prefetch, 2 steps deep: xkb[s][ct] = embk[tok[n][s]][ct*64 + w*16 + 4kg .. +3]
    floatx4 xkb[2][4];
#pragma unroll
    for (int s = 0; s < 2; ++s) {
        const float* base = embk + (long)tokLDS[n * T_ + s] * G_ + w * 16 + kg * 4;
#pragma unroll
        for (int ct = 0; ct < 4; ++ct)
            xkb[s][ct] = *(const floatx4*)(base + ct * 64);
    }

    auto step = [&](int t, int sel) {        // sel = t & 1 (constant at call site)
        // B-fragments = h^T_{t-1}: B[k][n] = h[n][k]; lane reads row n,
        // units kg*8..kg*8+7 (b0) and 32+kg*8..+7 (b1)
        const __bf16* hb = hbuf[sel ^ 1];
        bf16x8 b0 = *(const bf16x8*)(hb + n * S_H + kg * 8);
        bf16x8 b1 = *(const bf16x8*)(hb + n * S_H + 32 + kg * 8);

        // z^T tiles: acc[ct] = r1^T @ h^T + xk  (C-init = prefetched xk)
        floatx4 acc[4];
#pragma unroll
        for (int ct = 0; ct < 4; ++ct) {
            floatx4 a = xkb[sel][ct];
            a = __builtin_amdgcn_mfma_f32_16x16x32_bf16(afr[ct][0], b0, a, 0, 0, 0);
            a = __builtin_amdgcn_mfma_f32_16x16x32_bf16(afr[ct][1], b1, a, 0, 0, 0);
            acc[ct] = a;
        }

        // prefetch xk for t+2 into the slot just consumed (2-step window)
        if (t + 2 < T_) {
            const float* base = embk + (long)tokLDS[n * T_ + t + 2] * G_ + w * 16 + kg * 4;
#pragma unroll
            for (int ct = 0; ct < 4; ++ct)
                xkb[sel][ct] = *(const floatx4*)(base + ct * 64);
        }

        // gates: 4 dense cells/lane; acc[0]=i, acc[1]=f, acc[2]=g, acc[3]=o
        bf16x4 hv;
#pragma unroll
        for (int r = 0; r < 4; ++r) {
            float zi = acc[0][r], zf = acc[1][r], zg = acc[2][r], zo = acc[3][r];
            float cn = sigmoidf_(zf) * c[r] + sigmoidf_(zi) * tanhf_(zg);
            float hn = sigmoidf_(zo) * tanhf_(cn);
            c[r] = cn;
            hv[r] = (__bf16)hn;
        }
        // h_new: 4 consecutive units -> one b64 write
        *(bf16x4*)(&hbuf[sel][0] + n * S_H + w * 16 + kg * 4) = hv;

        __syncthreads();                     // h_t visible; WAR on hbuf
    };

    for (int t = 0; t < T_; t += 2) {
        step(t,     0);
        step(t + 1, 1);
    }

    // out[b] = sigmoid(h_final[b] . Wd + bd); h_79 in hbuf[1]
    if (tid < 16) {
        const __bf16* hb = hbuf[1] + tid * S_H;
        float s = bd[0];
#pragma unroll
        for (int u = 0; u < U_; ++u) s = fmaf((float)hb[u], Wd[u], s);
        out[bb + tid] = sigmoidf_(s);
    }
}

// ---------------------------------------------------------------------------
extern "C" void kernel_launch(void* const* d_in, const int* in_sizes, int n_in,
                              void* d_out, int out_size, void* d_ws, size_t ws_size,
                              hipStream_t stream) {
    const int*   tokens = (const int*)  d_in[0];
    const float* emb    = (const float*)d_in[1];
    // d_in[2..4] = k0, r0, b0 : dead in the reference (cell0 state unused)
    const float* k1     = (const float*)d_in[5];
    const float* r1     = (const float*)d_in[6];
    const float* b1     = (const float*)d_in[7];
    const float* Wd     = (const float*)d_in[8];
    const float* bd     = (const float*)d_in[9];
    float*       out    = (float*)d_out;

    float* embk = (float*)d_ws;              // V_*G_ floats = 10.24 MB

    embk_kernel<<<((V_ + 63) / 64) * 2, 256, 0, stream>>>(emb, k1, b1, embk);
    lstm_kernel<<<B_ / 16, 256, 0, stream>>>(tokens, embk, r1, Wd, bd, out);
}